// Round 2
// baseline (493.553 us; speedup 1.0000x reference)
//
#include <hip/hip_runtime.h>
#include <stdint.h>
#include <stddef.h>

#define S_LEN 2048
#define HID   3584
#define NH    28
#define NKV   4
#define HD    128
#define REP   7
#define KVD   512
// QK scale with log2(e) folded in: softmax uses exp2
#define QK_SCALE_L2E 0.12752462155f   // (1/sqrt(128)) * log2(e)

typedef unsigned short u16;
typedef short short8 __attribute__((ext_vector_type(8)));
typedef float f32x4 __attribute__((ext_vector_type(4)));

__device__ __forceinline__ u16 f2bf(float f) {
  union { float f; uint32_t u; } v; v.f = f;
  uint32_t r = v.u + 0x7fffu + ((v.u >> 16) & 1u);
  return (u16)(r >> 16);
}
__device__ __forceinline__ float bf2f(u16 u) {
  union { uint32_t u; float f; } v; v.u = ((uint32_t)u) << 16;
  return v.f;
}

#define GLL16(gp, lp) __builtin_amdgcn_global_load_lds( \
    (const __attribute__((address_space(1))) void*)(gp), \
    (__attribute__((address_space(3))) void*)(lp), 16, 0, 0)

// ---------------- f32 -> bf16 bulk convert (all 5 buffers, one launch) -------
__global__ __launch_bounds__(256) void cvt_all_kernel(
    const float* __restrict__ h, const float* __restrict__ qw,
    const float* __restrict__ kw, const float* __restrict__ vw,
    const float* __restrict__ ow,
    u16* __restrict__ hb, u16* __restrict__ qwb, u16* __restrict__ kwb,
    u16* __restrict__ vwb, u16* __restrict__ owb)
{
  const float* src; u16* dst; int n4;
  switch (blockIdx.y) {
    case 0: src = h;  dst = hb;  n4 = S_LEN * HID / 4; break;
    case 1: src = qw; dst = qwb; n4 = HID * HID / 4;   break;
    case 2: src = kw; dst = kwb; n4 = KVD * HID / 4;   break;
    case 3: src = vw; dst = vwb; n4 = KVD * HID / 4;   break;
    default: src = ow; dst = owb; n4 = HID * HID / 4;  break;
  }
  int i = blockIdx.x * blockDim.x + threadIdx.x;
  const int stride = gridDim.x * blockDim.x;
  for (; i < n4; i += stride) {
    float4 v = reinterpret_cast<const float4*>(src)[i];
    uint2 o;
    o.x = (uint32_t)f2bf(v.x) | ((uint32_t)f2bf(v.y) << 16);
    o.y = (uint32_t)f2bf(v.z) | ((uint32_t)f2bf(v.w) << 16);
    reinterpret_cast<uint2*>(dst)[i] = o;
  }
}

// ---------------- GEMM  C[M][N] = A[M][K] * W[N][K] (+bias) ----------------
// 128x128 tile, BK=64, 4 waves (2x2), each wave 64x64 (4x4 frags of 16x16).
// LDS tiles XOR-swizzled: LDS slot (row, c) holds global col c ^ ((row&7)*8).
template<int OUT_F32, int HAS_BIAS>
__device__ __forceinline__ void gemm_bt_tile(
    u16* As, u16* Bs,
    const u16* __restrict__ A, const u16* __restrict__ W,
    const float* __restrict__ bias, void* __restrict__ C,
    int ldC, int K, int m0, int n0)
{
  const int t  = threadIdx.x;
  const int l  = t & 63;
  const int w  = t >> 6;
  const int lr = l & 15;
  const int lg = l >> 4;
  const int wr = (w >> 1) << 6;
  const int wc = (w & 1) << 6;
  const int sw = (lr & 7) << 3;

  const f32x4 fz = {0.f, 0.f, 0.f, 0.f};
  f32x4 acc[4][4];
#pragma unroll
  for (int i = 0; i < 4; ++i)
#pragma unroll
    for (int j = 0; j < 4; ++j) acc[i][j] = fz;

  for (int k0 = 0; k0 < K; k0 += 64) {
    __syncthreads();
#pragma unroll
    for (int i = 0; i < 4; ++i) {
      const int e   = (i * 256 + t) * 8;
      const int row = e >> 6;
      const int cs  = (e & 63) ^ ((row & 7) << 3);
      GLL16(A + (size_t)(m0 + row) * K + k0 + cs, As + e);
      GLL16(W + (size_t)(n0 + row) * K + k0 + cs, Bs + e);
    }
    __syncthreads();
#pragma unroll
    for (int kk = 0; kk < 2; ++kk) {
      short8 af[4], bfr[4];
#pragma unroll
      for (int mi = 0; mi < 4; ++mi)
        af[mi] = *(const short8*)(As + (wr + mi * 16 + lr) * 64 + ((kk * 32 + lg * 8) ^ sw));
#pragma unroll
      for (int ni = 0; ni < 4; ++ni)
        bfr[ni] = *(const short8*)(Bs + (wc + ni * 16 + lr) * 64 + ((kk * 32 + lg * 8) ^ sw));
#pragma unroll
      for (int mi = 0; mi < 4; ++mi)
#pragma unroll
        for (int ni = 0; ni < 4; ++ni)
          acc[mi][ni] = __builtin_amdgcn_mfma_f32_16x16x32_bf16(af[mi], bfr[ni], acc[mi][ni], 0, 0, 0);
    }
  }

#pragma unroll
  for (int ni = 0; ni < 4; ++ni) {
    const int n = n0 + wc + ni * 16 + lr;
    float bv = 0.f;
    if (HAS_BIAS) bv = bias[n];
#pragma unroll
    for (int mi = 0; mi < 4; ++mi) {
#pragma unroll
      for (int r = 0; r < 4; ++r) {
        const int m = m0 + wr + mi * 16 + lg * 4 + r;
        const float vv = acc[mi][ni][r] + bv;
        if (OUT_F32) ((float*)C)[(size_t)m * ldC + n] = vv;
        else         ((u16*)C)[(size_t)m * ldC + n]   = f2bf(vv);
      }
    }
  }
}

__global__ __launch_bounds__(256) void qkv_gemm_kernel(
    const u16* __restrict__ hb,
    const u16* __restrict__ qwb, const u16* __restrict__ kwb, const u16* __restrict__ vwb,
    const float* __restrict__ qbias, const float* __restrict__ kbias, const float* __restrict__ vbias,
    u16* __restrict__ qo, u16* __restrict__ ko, u16* __restrict__ vo)
{
  __shared__ u16 As[128 * 64];
  __shared__ u16 Bs[128 * 64];
  const int m0 = blockIdx.x * 128;
  const int by = blockIdx.y;
  if (by < 28)
    gemm_bt_tile<0, 1>(As, Bs, hb, qwb, qbias, qo, HID, HID, m0, by * 128);
  else if (by < 32)
    gemm_bt_tile<0, 1>(As, Bs, hb, kwb, kbias, ko, KVD, HID, m0, (by - 28) * 128);
  else
    gemm_bt_tile<0, 1>(As, Bs, hb, vwb, vbias, vo, KVD, HID, m0, (by - 32) * 128);
}

__global__ __launch_bounds__(256) void oproj_gemm_kernel(
    const u16* __restrict__ ao, const u16* __restrict__ owb, float* __restrict__ out)
{
  __shared__ u16 As[128 * 64];
  __shared__ u16 Bs[128 * 64];
  gemm_bt_tile<1, 0>(As, Bs, ao, owb, nullptr, out, HID, HID,
                     blockIdx.x * 128, blockIdx.y * 128);
}

// ---------------- RoPE (Q gets scale*log2e folded in; softmax uses exp2) ----
__global__ __launch_bounds__(256) void rope_kernel(
    u16* __restrict__ q, u16* __restrict__ k,
    const float* __restrict__ cosb, const float* __restrict__ sinb)
{
  const int idx = blockIdx.x * 256 + threadIdx.x;  // S*32heads*64
  const int d  = idx & 63;
  const int ht = (idx >> 6) & 31;
  const int s  = idx >> 11;
  const float c  = cosb[s * HD + d];
  const float sn = sinb[s * HD + d];
  u16* base;
  float scale;
  if (ht < NH) { base = q + (size_t)s * HID + ht * HD; scale = QK_SCALE_L2E; }
  else         { base = k + (size_t)s * KVD + (ht - NH) * HD; scale = 1.0f; }
  const float x1 = bf2f(base[d]);
  const float x2 = bf2f(base[d + 64]);
  base[d]      = f2bf((x1 * c - x2 * sn) * scale);
  base[d + 64] = f2bf((x1 * sn + x2 * c) * scale);
}

// ---------------- V transpose: [S][KVD] -> [KVD][S] ----------------
__global__ __launch_bounds__(256) void vtrans_kernel(
    const u16* __restrict__ v, u16* __restrict__ vt)
{
  __shared__ u16 tile[32][33];
  const int bs = blockIdx.x * 32;
  const int bd = blockIdx.y * 32;
  const int tx = threadIdx.x & 31;
  const int ty = threadIdx.x >> 5;
#pragma unroll
  for (int i = 0; i < 4; ++i) {
    const int r = ty * 4 + i;
    tile[r][tx] = v[(size_t)(bs + r) * KVD + bd + tx];
  }
  __syncthreads();
#pragma unroll
  for (int i = 0; i < 4; ++i) {
    const int r = ty * 4 + i;
    vt[(size_t)(bd + r) * S_LEN + bs + tx] = tile[tx][r];
  }
}

// ---------------- Flash attention (causal, GQA) ----------------
// Barrier-free: K and V^T fragments read directly from global (L2-resident).
// Block = 128 threads (2 waves). Each wave owns 16 q-rows; block covers a
// 32-row tile. Causal balance: block does tile bx AND tile 63-bx (33 KV
// iterations total, uniform across all 896 blocks).
__global__ __launch_bounds__(128) void attn_kernel(
    const u16* __restrict__ qb, const u16* __restrict__ kb,
    const u16* __restrict__ vtb, u16* __restrict__ ao)
{
  __shared__ u16 Ps[2][16 * 64];  // per-wave P scratch, swizzled

  const int h   = blockIdx.y;
  const int kvh = h / REP;
  const int t   = threadIdx.x;
  const int w   = t >> 6;
  const int l   = t & 63;
  const int lr  = l & 15;
  const int lg  = l >> 4;
  const int sw  = (lr & 7) << 3;
  const f32x4 fz = {0.f, 0.f, 0.f, 0.f};

  const u16* kbh  = kb + kvh * HD;
  const u16* vtbh = vtb + (size_t)kvh * HD * S_LEN;

#pragma unroll 1
  for (int half = 0; half < 2; ++half) {
    const int tile = (half == 0) ? (int)blockIdx.x : 63 - (int)blockIdx.x;
    const int q0w  = tile * 32 + w * 16;  // wave's first q row

    short8 qf[4];
    {
      const u16* qrow = qb + (size_t)(q0w + lr) * HID + h * HD;
#pragma unroll
      for (int dk = 0; dk < 4; ++dk)
        qf[dk] = *(const short8*)(qrow + dk * 32 + lg * 8);
    }

    float m_r[4], l_r[4];
    f32x4 o_acc[8];
#pragma unroll
    for (int r = 0; r < 4; ++r) { m_r[r] = -1e30f; l_r[r] = 0.f; }
#pragma unroll
    for (int db = 0; db < 8; ++db) o_acc[db] = fz;

    const int kvmax = ((tile * 32 + 31) >> 6) << 6;  // last kv tile base
#pragma unroll 1
    for (int kv0 = 0; kv0 <= kvmax; kv0 += 64) {
      // ---- QK^T : S[16 q x 64 kv] per wave, K frags direct from global ----
      f32x4 sacc[4];
#pragma unroll
      for (int kvt = 0; kvt < 4; ++kvt) sacc[kvt] = fz;
#pragma unroll
      for (int kvt = 0; kvt < 4; ++kvt) {
        const u16* krow = kbh + (size_t)(kv0 + kvt * 16 + lr) * KVD + lg * 8;
#pragma unroll
        for (int dk = 0; dk < 4; ++dk) {
          const short8 kf = *(const short8*)(krow + dk * 32);
          sacc[kvt] = __builtin_amdgcn_mfma_f32_16x16x32_bf16(qf[dk], kf, sacc[kvt], 0, 0, 0);
        }
      }

      if (kv0 == kvmax) {  // causal mask on the last tile
#pragma unroll
        for (int kvt = 0; kvt < 4; ++kvt) {
          const int col = kv0 + kvt * 16 + lr;
#pragma unroll
          for (int r = 0; r < 4; ++r) {
            if (col > q0w + lg * 4 + r) sacc[kvt][r] = -1e30f;
          }
        }
      }

      // ---- online softmax (exp2; rows on 16-lane groups) ----
#pragma unroll
      for (int r = 0; r < 4; ++r) {
        float tm = fmaxf(fmaxf(sacc[0][r], sacc[1][r]), fmaxf(sacc[2][r], sacc[3][r]));
        tm = fmaxf(tm, __shfl_xor(tm, 1));
        tm = fmaxf(tm, __shfl_xor(tm, 2));
        tm = fmaxf(tm, __shfl_xor(tm, 4));
        tm = fmaxf(tm, __shfl_xor(tm, 8));
        const float mn = fmaxf(m_r[r], tm);
        const float alpha = exp2f(m_r[r] - mn);
        float rs = 0.f;
#pragma unroll
        for (int kvt = 0; kvt < 4; ++kvt) {
          const float p = exp2f(sacc[kvt][r] - mn);
          sacc[kvt][r] = p;
          rs += p;
        }
        rs += __shfl_xor(rs, 1);
        rs += __shfl_xor(rs, 2);
        rs += __shfl_xor(rs, 4);
        rs += __shfl_xor(rs, 8);
        l_r[r] = l_r[r] * alpha + rs;
        m_r[r] = mn;
#pragma unroll
        for (int db = 0; db < 8; ++db) o_acc[db][r] *= alpha;
      }

      // ---- P -> per-wave LDS (swizzled), no block barrier needed ----
#pragma unroll
      for (int kvt = 0; kvt < 4; ++kvt) {
#pragma unroll
        for (int r = 0; r < 4; ++r) {
          const int prow = lg * 4 + r;
          Ps[w][prow * 64 + ((kvt * 16 + lr) ^ ((prow & 7) << 3))] = f2bf(sacc[kvt][r]);
        }
      }

      short8 pf[2];
#pragma unroll
      for (int ks = 0; ks < 2; ++ks)
        pf[ks] = *(const short8*)(&Ps[w][0] + lr * 64 + ((ks * 32 + lg * 8) ^ sw));

      // ---- PV : V^T frags direct from global ----
#pragma unroll
      for (int db = 0; db < 8; ++db) {
        const u16* vrow = vtbh + (size_t)(db * 16 + lr) * S_LEN + kv0 + lg * 8;
#pragma unroll
        for (int ks = 0; ks < 2; ++ks) {
          const short8 vf = *(const short8*)(vrow + ks * 32);
          o_acc[db] = __builtin_amdgcn_mfma_f32_16x16x32_bf16(pf[ks], vf, o_acc[db], 0, 0, 0);
        }
      }
    }

    // ---- epilogue ----
#pragma unroll
    for (int r = 0; r < 4; ++r) {
      const float inv = 1.0f / l_r[r];
      u16* orow = ao + (size_t)(q0w + lg * 4 + r) * HID + h * HD;
#pragma unroll
      for (int db = 0; db < 8; ++db)
        orow[db * 16 + lr] = f2bf(o_acc[db][r] * inv);
    }
  }
}

// ---------------- launch ----------------
extern "C" void kernel_launch(void* const* d_in, const int* in_sizes, int n_in,
                              void* d_out, int out_size, void* d_ws, size_t ws_size,
                              hipStream_t stream) {
  const float* hidden = (const float*)d_in[0];
  const float* cosb = (const float*)d_in[2];
  const float* sinb = (const float*)d_in[3];
  const float* q_w  = (const float*)d_in[4];
  const float* q_b  = (const float*)d_in[5];
  const float* k_w  = (const float*)d_in[6];
  const float* k_b  = (const float*)d_in[7];
  const float* v_w  = (const float*)d_in[8];
  const float* v_b  = (const float*)d_in[9];
  const float* o_w  = (const float*)d_in[10];
  float* out = (float*)d_out;

  char* p = (char*)d_ws;
  u16* hb   = (u16*)p; p += (size_t)S_LEN * HID * 2;
  u16* qwb  = (u16*)p; p += (size_t)HID * HID * 2;
  u16* kwb  = (u16*)p; p += (size_t)KVD * HID * 2;
  u16* vwb  = (u16*)p; p += (size_t)KVD * HID * 2;
  u16* owb  = (u16*)p; p += (size_t)HID * HID * 2;
  u16* qbuf = (u16*)p; p += (size_t)S_LEN * HID * 2;
  u16* kbuf = (u16*)p; p += (size_t)S_LEN * KVD * 2;
  u16* vbuf = (u16*)p; p += (size_t)S_LEN * KVD * 2;
  u16* vtb  = (u16*)p; p += (size_t)KVD * S_LEN * 2;
  u16* ao   = (u16*)p; p += (size_t)S_LEN * HID * 2;
  if ((size_t)(p - (char*)d_ws) > ws_size) return;

  cvt_all_kernel<<<dim3(1024, 5), 256, 0, stream>>>(
      hidden, q_w, k_w, v_w, o_w, hb, qwb, kwb, vwb, owb);

  qkv_gemm_kernel<<<dim3(16, 36), 256, 0, stream>>>(hb, qwb, kwb, vwb,
                                                    q_b, k_b, v_b,
                                                    qbuf, kbuf, vbuf);
  rope_kernel<<<(S_LEN * 32 * 64) / 256, 256, 0, stream>>>(qbuf, kbuf, cosb, sinb);
  vtrans_kernel<<<dim3(S_LEN / 32, KVD / 32), 256, 0, stream>>>(vbuf, vtb);
  attn_kernel<<<dim3(32, 28), 128, 0, stream>>>(qbuf, kbuf, vtb, ao);
  oproj_gemm_kernel<<<dim3(16, 28), 256, 0, stream>>>(ao, owb, out);
}

// Round 3
// 340.170 us; speedup vs baseline: 1.4509x; 1.4509x over previous
//
#include <hip/hip_runtime.h>
#include <stdint.h>
#include <stddef.h>

#define S_LEN 2048
#define HID   3584
#define NH    28
#define NKV   4
#define HD    128
#define REP   7
#define KVD   512
// QK scale with log2(e) folded in: softmax uses exp2
#define QK_SCALE_L2E 0.12752462155f   // (1/sqrt(128)) * log2(e)

typedef unsigned short u16;
typedef short short8 __attribute__((ext_vector_type(8)));
typedef float f32x4 __attribute__((ext_vector_type(4)));

__device__ __forceinline__ u16 f2bf(float f) {
  union { float f; uint32_t u; } v; v.f = f;
  uint32_t r = v.u + 0x7fffu + ((v.u >> 16) & 1u);
  return (u16)(r >> 16);
}
__device__ __forceinline__ float bf2f(u16 u) {
  union { uint32_t u; float f; } v; v.u = ((uint32_t)u) << 16;
  return v.f;
}

#define GLL16(gp, lp) __builtin_amdgcn_global_load_lds( \
    (const __attribute__((address_space(1))) void*)(gp), \
    (__attribute__((address_space(3))) void*)(lp), 16, 0, 0)

// ---------------- f32 -> bf16 bulk convert (all 5 buffers, one launch) -------
__global__ __launch_bounds__(256) void cvt_all_kernel(
    const float* __restrict__ h, const float* __restrict__ qw,
    const float* __restrict__ kw, const float* __restrict__ vw,
    const float* __restrict__ ow,
    u16* __restrict__ hb, u16* __restrict__ qwb, u16* __restrict__ kwb,
    u16* __restrict__ vwb, u16* __restrict__ owb)
{
  const float* src; u16* dst; int n4;
  switch (blockIdx.y) {
    case 0: src = h;  dst = hb;  n4 = S_LEN * HID / 4; break;
    case 1: src = qw; dst = qwb; n4 = HID * HID / 4;   break;
    case 2: src = kw; dst = kwb; n4 = KVD * HID / 4;   break;
    case 3: src = vw; dst = vwb; n4 = KVD * HID / 4;   break;
    default: src = ow; dst = owb; n4 = HID * HID / 4;  break;
  }
  int i = blockIdx.x * blockDim.x + threadIdx.x;
  const int stride = gridDim.x * blockDim.x;
  for (; i < n4; i += stride) {
    float4 v = reinterpret_cast<const float4*>(src)[i];
    uint2 o;
    o.x = (uint32_t)f2bf(v.x) | ((uint32_t)f2bf(v.y) << 16);
    o.y = (uint32_t)f2bf(v.z) | ((uint32_t)f2bf(v.w) << 16);
    reinterpret_cast<uint2*>(dst)[i] = o;
  }
}

// ---------------- GEMM  C[M][N] = A[M][K] * W[N][K] (+bias) ----------------
// 128x128 tile, BK=64, 4 waves (2x2), each wave 64x64 (4x4 frags of 16x16).
template<int OUT_F32, int HAS_BIAS>
__device__ __forceinline__ void gemm_bt_tile(
    u16* As, u16* Bs,
    const u16* __restrict__ A, const u16* __restrict__ W,
    const float* __restrict__ bias, void* __restrict__ C,
    int ldC, int K, int m0, int n0)
{
  const int t  = threadIdx.x;
  const int l  = t & 63;
  const int w  = t >> 6;
  const int lr = l & 15;
  const int lg = l >> 4;
  const int wr = (w >> 1) << 6;
  const int wc = (w & 1) << 6;
  const int sw = (lr & 7) << 3;

  const f32x4 fz = {0.f, 0.f, 0.f, 0.f};
  f32x4 acc[4][4];
#pragma unroll
  for (int i = 0; i < 4; ++i)
#pragma unroll
    for (int j = 0; j < 4; ++j) acc[i][j] = fz;

  for (int k0 = 0; k0 < K; k0 += 64) {
    __syncthreads();
#pragma unroll
    for (int i = 0; i < 4; ++i) {
      const int e   = (i * 256 + t) * 8;
      const int row = e >> 6;
      const int cs  = (e & 63) ^ ((row & 7) << 3);
      GLL16(A + (size_t)(m0 + row) * K + k0 + cs, As + e);
      GLL16(W + (size_t)(n0 + row) * K + k0 + cs, Bs + e);
    }
    __syncthreads();
#pragma unroll
    for (int kk = 0; kk < 2; ++kk) {
      short8 af[4], bfr[4];
#pragma unroll
      for (int mi = 0; mi < 4; ++mi)
        af[mi] = *(const short8*)(As + (wr + mi * 16 + lr) * 64 + ((kk * 32 + lg * 8) ^ sw));
#pragma unroll
      for (int ni = 0; ni < 4; ++ni)
        bfr[ni] = *(const short8*)(Bs + (wc + ni * 16 + lr) * 64 + ((kk * 32 + lg * 8) ^ sw));
#pragma unroll
      for (int mi = 0; mi < 4; ++mi)
#pragma unroll
        for (int ni = 0; ni < 4; ++ni)
          acc[mi][ni] = __builtin_amdgcn_mfma_f32_16x16x32_bf16(af[mi], bfr[ni], acc[mi][ni], 0, 0, 0);
    }
  }

#pragma unroll
  for (int ni = 0; ni < 4; ++ni) {
    const int n = n0 + wc + ni * 16 + lr;
    float bv = 0.f;
    if (HAS_BIAS) bv = bias[n];
#pragma unroll
    for (int mi = 0; mi < 4; ++mi) {
#pragma unroll
      for (int r = 0; r < 4; ++r) {
        const int m = m0 + wr + mi * 16 + lg * 4 + r;
        const float vv = acc[mi][ni][r] + bv;
        if (OUT_F32) ((float*)C)[(size_t)m * ldC + n] = vv;
        else         ((u16*)C)[(size_t)m * ldC + n]   = f2bf(vv);
      }
    }
  }
}

__global__ __launch_bounds__(256) void qkv_gemm_kernel(
    const u16* __restrict__ hb,
    const u16* __restrict__ qwb, const u16* __restrict__ kwb, const u16* __restrict__ vwb,
    const float* __restrict__ qbias, const float* __restrict__ kbias, const float* __restrict__ vbias,
    u16* __restrict__ qo, u16* __restrict__ ko, u16* __restrict__ vo)
{
  __shared__ u16 As[128 * 64];
  __shared__ u16 Bs[128 * 64];
  const int m0 = blockIdx.x * 128;
  const int by = blockIdx.y;
  if (by < 28)
    gemm_bt_tile<0, 1>(As, Bs, hb, qwb, qbias, qo, HID, HID, m0, by * 128);
  else if (by < 32)
    gemm_bt_tile<0, 1>(As, Bs, hb, kwb, kbias, ko, KVD, HID, m0, (by - 28) * 128);
  else
    gemm_bt_tile<0, 1>(As, Bs, hb, vwb, vbias, vo, KVD, HID, m0, (by - 32) * 128);
}

__global__ __launch_bounds__(256) void oproj_gemm_kernel(
    const u16* __restrict__ ao, const u16* __restrict__ owb, float* __restrict__ out)
{
  __shared__ u16 As[128 * 64];
  __shared__ u16 Bs[128 * 64];
  gemm_bt_tile<1, 0>(As, Bs, ao, owb, nullptr, out, HID, HID,
                     blockIdx.x * 128, blockIdx.y * 128);
}

// ---------------- RoPE (Q gets scale*log2e folded in; softmax uses exp2) ----
__global__ __launch_bounds__(256) void rope_kernel(
    u16* __restrict__ q, u16* __restrict__ k,
    const float* __restrict__ cosb, const float* __restrict__ sinb)
{
  const int idx = blockIdx.x * 256 + threadIdx.x;  // S*32heads*64
  const int d  = idx & 63;
  const int ht = (idx >> 6) & 31;
  const int s  = idx >> 11;
  const float c  = cosb[s * HD + d];
  const float sn = sinb[s * HD + d];
  u16* base;
  float scale;
  if (ht < NH) { base = q + (size_t)s * HID + ht * HD; scale = QK_SCALE_L2E; }
  else         { base = k + (size_t)s * KVD + (ht - NH) * HD; scale = 1.0f; }
  const float x1 = bf2f(base[d]);
  const float x2 = bf2f(base[d + 64]);
  base[d]      = f2bf((x1 * c - x2 * sn) * scale);
  base[d + 64] = f2bf((x1 * sn + x2 * c) * scale);
}

// ---------------- V transpose: [S][KVD] -> [KVD][S] ----------------
__global__ __launch_bounds__(256) void vtrans_kernel(
    const u16* __restrict__ v, u16* __restrict__ vt)
{
  __shared__ u16 tile[32][33];
  const int bs = blockIdx.x * 32;
  const int bd = blockIdx.y * 32;
  const int tx = threadIdx.x & 31;
  const int ty = threadIdx.x >> 5;
#pragma unroll
  for (int i = 0; i < 4; ++i) {
    const int r = ty * 4 + i;
    tile[r][tx] = v[(size_t)(bs + r) * KVD + bd + tx];
  }
  __syncthreads();
#pragma unroll
  for (int i = 0; i < 4; ++i) {
    const int r = ty * 4 + i;
    vt[(size_t)(bd + r) * S_LEN + bs + tx] = tile[tx][r];
  }
}

// ---------------- Flash attention (causal, GQA) ----------------
// Block = 256 thr (4 waves x 16 q-rows = 64-row q-tile). Causal balance:
// block processes q-tile lo=bx and hi=31-bx sequentially -> 33 KV iters
// uniform. K/V^T staged to LDS, double-buffered, prefetch issued before
// compute (2-phase pipeline); one barrier per iteration.
__global__ __launch_bounds__(256) void attn_kernel(
    const u16* __restrict__ qb, const u16* __restrict__ kb,
    const u16* __restrict__ vtb, u16* __restrict__ ao)
{
  __shared__ u16 Ks[2][64 * 128];   // [kv][d], swizzled
  __shared__ u16 Vts[2][128 * 64];  // [d][kv], swizzled
  __shared__ u16 Ps[4][16 * 64];    // per-wave P, swizzled

  const int h   = blockIdx.y;
  const int kvh = h / REP;
  const int lo  = blockIdx.x;       // 0..15
  const int hi  = 31 - lo;
  const int t   = threadIdx.x;
  const int w   = t >> 6;
  const int l   = t & 63;
  const int lr  = l & 15;
  const int lg  = l >> 4;
  const int sw  = (lr & 7) << 3;
  const f32x4 fz = {0.f, 0.f, 0.f, 0.f};

  const u16* kbh  = kb + kvh * HD;
  const u16* vtbh = vtb + (size_t)kvh * HD * S_LEN;

  int tile = lo;
  short8 qf[4];
  {
    const u16* qrow = qb + (size_t)(tile * 64 + w * 16 + lr) * HID + h * HD;
#pragma unroll
    for (int dk = 0; dk < 4; ++dk)
      qf[dk] = *(const short8*)(qrow + dk * 32 + lg * 8);
  }

  float m_r[4], l_r[4];
  f32x4 o_acc[8];
#pragma unroll
  for (int r = 0; r < 4; ++r) { m_r[r] = -1e30f; l_r[r] = 0.f; }
#pragma unroll
  for (int db = 0; db < 8; ++db) o_acc[db] = fz;

  // ---- prologue: stage kv tile 0 into buf 0 ----
#pragma unroll
  for (int i = 0; i < 4; ++i) {
    const int e  = (i * 256 + t) * 8;
    const int rk = e >> 7;
    const int ck = (e & 127) ^ ((rk & 7) << 3);
    GLL16(kbh + (size_t)rk * KVD + ck, &Ks[0][0] + e);
    const int rv = e >> 6;
    const int cv = (e & 63) ^ ((rv & 7) << 3);
    GLL16(vtbh + (size_t)rv * S_LEN + cv, &Vts[0][0] + e);
  }
  __syncthreads();

#pragma unroll 1
  for (int j = 0; j < 33; ++j) {
    const int buf = j & 1;
    // ---- issue prefetch of next kv tile into buf^1 ----
    if (j + 1 < 33) {
      const int jn  = j + 1;
      const int kvn = ((jn <= lo) ? jn : (jn - lo - 1)) * 64;
#pragma unroll
      for (int i = 0; i < 4; ++i) {
        const int e  = (i * 256 + t) * 8;
        const int rk = e >> 7;
        const int ck = (e & 127) ^ ((rk & 7) << 3);
        GLL16(kbh + (size_t)(kvn + rk) * KVD + ck, &Ks[buf ^ 1][0] + e);
        const int rv = e >> 6;
        const int cv = (e & 63) ^ ((rv & 7) << 3);
        GLL16(vtbh + (size_t)rv * S_LEN + kvn + cv, &Vts[buf ^ 1][0] + e);
      }
    }

    const int kv0 = ((j <= lo) ? j : (j - lo - 1)) * 64;
    const u16* ks = &Ks[buf][0];
    const u16* vs = &Vts[buf][0];

    // ---- QK^T : S[16 q x 64 kv] per wave ----
    f32x4 sacc[4];
#pragma unroll
    for (int kvt = 0; kvt < 4; ++kvt) sacc[kvt] = fz;
    __builtin_amdgcn_s_setprio(1);
#pragma unroll
    for (int kvt = 0; kvt < 4; ++kvt) {
#pragma unroll
      for (int dk = 0; dk < 4; ++dk) {
        const short8 kf = *(const short8*)(ks + (kvt * 16 + lr) * 128 + ((dk * 32 + lg * 8) ^ sw));
        sacc[kvt] = __builtin_amdgcn_mfma_f32_16x16x32_bf16(qf[dk], kf, sacc[kvt], 0, 0, 0);
      }
    }
    __builtin_amdgcn_s_setprio(0);

    const bool last_of_half = (j == lo) || (j == 32);
    if (last_of_half) {  // diagonal tile: causal mask
      const int q0w = tile * 64 + w * 16;
#pragma unroll
      for (int kvt = 0; kvt < 4; ++kvt) {
        const int col = kv0 + kvt * 16 + lr;
#pragma unroll
        for (int r = 0; r < 4; ++r) {
          if (col > q0w + lg * 4 + r) sacc[kvt][r] = -1e30f;
        }
      }
    }

    // ---- online softmax (exp2; rows on 16-lane groups) ----
#pragma unroll
    for (int r = 0; r < 4; ++r) {
      float tm = fmaxf(fmaxf(sacc[0][r], sacc[1][r]), fmaxf(sacc[2][r], sacc[3][r]));
      tm = fmaxf(tm, __shfl_xor(tm, 1));
      tm = fmaxf(tm, __shfl_xor(tm, 2));
      tm = fmaxf(tm, __shfl_xor(tm, 4));
      tm = fmaxf(tm, __shfl_xor(tm, 8));
      const float mn = fmaxf(m_r[r], tm);
      const float alpha = exp2f(m_r[r] - mn);
      float rs = 0.f;
#pragma unroll
      for (int kvt = 0; kvt < 4; ++kvt) {
        const float p = exp2f(sacc[kvt][r] - mn);
        sacc[kvt][r] = p;
        rs += p;
      }
      rs += __shfl_xor(rs, 1);
      rs += __shfl_xor(rs, 2);
      rs += __shfl_xor(rs, 4);
      rs += __shfl_xor(rs, 8);
      l_r[r] = l_r[r] * alpha + rs;
      m_r[r] = mn;
#pragma unroll
      for (int db = 0; db < 8; ++db) o_acc[db][r] *= alpha;
    }

    // ---- P -> per-wave LDS (swizzled) ----
#pragma unroll
    for (int kvt = 0; kvt < 4; ++kvt) {
#pragma unroll
      for (int r = 0; r < 4; ++r) {
        const int prow = lg * 4 + r;
        Ps[w][prow * 64 + ((kvt * 16 + lr) ^ ((prow & 7) << 3))] = f2bf(sacc[kvt][r]);
      }
    }

    short8 pf[2];
#pragma unroll
    for (int ks2 = 0; ks2 < 2; ++ks2)
      pf[ks2] = *(const short8*)(&Ps[w][0] + lr * 64 + ((ks2 * 32 + lg * 8) ^ sw));

    // ---- PV ----
    __builtin_amdgcn_s_setprio(1);
#pragma unroll
    for (int db = 0; db < 8; ++db) {
#pragma unroll
      for (int ks2 = 0; ks2 < 2; ++ks2) {
        const short8 vf = *(const short8*)(vs + (db * 16 + lr) * 64 + ((ks2 * 32 + lg * 8) ^ sw));
        o_acc[db] = __builtin_amdgcn_mfma_f32_16x16x32_bf16(pf[ks2], vf, o_acc[db], 0, 0, 0);
      }
    }
    __builtin_amdgcn_s_setprio(0);

    // ---- end-of-half: epilogue + switch to hi tile ----
    if (last_of_half) {
#pragma unroll
      for (int r = 0; r < 4; ++r) {
        const float inv = 1.0f / l_r[r];
        u16* orow = ao + (size_t)(tile * 64 + w * 16 + lg * 4 + r) * HID + h * HD;
#pragma unroll
        for (int db = 0; db < 8; ++db)
          orow[db * 16 + lr] = f2bf(o_acc[db][r] * inv);
      }
      if (j != 32) {
        tile = hi;
        const u16* qrow = qb + (size_t)(tile * 64 + w * 16 + lr) * HID + h * HD;
#pragma unroll
        for (int dk = 0; dk < 4; ++dk)
          qf[dk] = *(const short8*)(qrow + dk * 32 + lg * 8);
#pragma unroll
        for (int r = 0; r < 4; ++r) { m_r[r] = -1e30f; l_r[r] = 0.f; }
#pragma unroll
        for (int db = 0; db < 8; ++db) o_acc[db] = fz;
      }
    }
    __syncthreads();  // drains prefetch + guards buf reuse
  }
}

// ---------------- launch ----------------
extern "C" void kernel_launch(void* const* d_in, const int* in_sizes, int n_in,
                              void* d_out, int out_size, void* d_ws, size_t ws_size,
                              hipStream_t stream) {
  const float* hidden = (const float*)d_in[0];
  const float* cosb = (const float*)d_in[2];
  const float* sinb = (const float*)d_in[3];
  const float* q_w  = (const float*)d_in[4];
  const float* q_b  = (const float*)d_in[5];
  const float* k_w  = (const float*)d_in[6];
  const float* k_b  = (const float*)d_in[7];
  const float* v_w  = (const float*)d_in[8];
  const float* v_b  = (const float*)d_in[9];
  const float* o_w  = (const float*)d_in[10];
  float* out = (float*)d_out;

  char* p = (char*)d_ws;
  u16* hb   = (u16*)p; p += (size_t)S_LEN * HID * 2;
  u16* qwb  = (u16*)p; p += (size_t)HID * HID * 2;
  u16* kwb  = (u16*)p; p += (size_t)KVD * HID * 2;
  u16* vwb  = (u16*)p; p += (size_t)KVD * HID * 2;
  u16* owb  = (u16*)p; p += (size_t)HID * HID * 2;
  u16* qbuf = (u16*)p; p += (size_t)S_LEN * HID * 2;
  u16* kbuf = (u16*)p; p += (size_t)S_LEN * KVD * 2;
  u16* vbuf = (u16*)p; p += (size_t)S_LEN * KVD * 2;
  u16* vtb  = (u16*)p; p += (size_t)KVD * S_LEN * 2;
  u16* ao   = (u16*)p; p += (size_t)S_LEN * HID * 2;
  if ((size_t)(p - (char*)d_ws) > ws_size) return;

  cvt_all_kernel<<<dim3(1024, 5), 256, 0, stream>>>(
      hidden, q_w, k_w, v_w, o_w, hb, qwb, kwb, vwb, owb);

  qkv_gemm_kernel<<<dim3(16, 36), 256, 0, stream>>>(hb, qwb, kwb, vwb,
                                                    q_b, k_b, v_b,
                                                    qbuf, kbuf, vbuf);
  rope_kernel<<<(S_LEN * 32 * 64) / 256, 256, 0, stream>>>(qbuf, kbuf, cosb, sinb);
  vtrans_kernel<<<dim3(S_LEN / 32, KVD / 32), 256, 0, stream>>>(vbuf, vtb);
  attn_kernel<<<dim3(16, 28), 256, 0, stream>>>(qbuf, kbuf, vtb, ao);
  oproj_gemm_kernel<<<dim3(16, 28), 256, 0, stream>>>(ao, owb, out);
}